// Round 6
// baseline (402.545 us; speedup 1.0000x reference)
//
#include <hip/hip_runtime.h>
#include <math.h>

#define B_ 64
#define T_ 1024
#define D_ 512
#define U_ 1024

typedef __bf16 bf16x8 __attribute__((ext_vector_type(8)));
typedef float f32x16 __attribute__((ext_vector_type(16)));
typedef unsigned int u32;

__device__ __forceinline__ float fast_tanh(float x) {
    float ax = fabsf(x);
    float e = __expf(2.0f * ax);
    float r = 1.0f - __fdividef(2.0f, e + 1.0f);
    return copysignf(r, x);
}

__device__ __forceinline__ u32 f2bf_pk(float lo, float hi) {
    u32 a = __float_as_uint(lo) + 0x8000u;
    u32 b = __float_as_uint(hi) + 0x8000u;
    return (a >> 16) | (b & 0xffff0000u);
}

// K0: W1 [D][U] fp32 -> W1T [U][D] bf16
__global__ __launch_bounds__(256) void w1t_kernel(
    const float* __restrict__ W1, unsigned short* __restrict__ W1T) {
    const int gidx = blockIdx.x * 256 + threadIdx.x;
    const int u  = gidx & (U_ - 1);
    const int d0 = (gidx >> 10) * 8;
    float f[8];
#pragma unroll
    for (int i = 0; i < 8; ++i) f[i] = W1[(size_t)(d0 + i) * U_ + u];
    uint4 w;
    w.x = f2bf_pk(f[0], f[1]);
    w.y = f2bf_pk(f[2], f[3]);
    w.z = f2bf_pk(f[4], f[5]);
    w.w = f2bf_pk(f[6], f[7]);
    *(uint4*)&W1T[(size_t)u * D_ + d0] = w;
}

// K1: ph[b][u] = hidden[b,:]·W2[:,u] + W2_b[u] + W1_b[u]; grid (U/256, B)
__global__ __launch_bounds__(256) void ph_kernel(
    const float* __restrict__ hidden, const float* __restrict__ W2,
    const float* __restrict__ W2b, const float* __restrict__ W1b,
    float* __restrict__ ph) {
    const int u = blockIdx.x * 256 + threadIdx.x;
    const int b = blockIdx.y;
    const float* h = hidden + b * D_;
    float acc = 0.f;
#pragma unroll 8
    for (int d = 0; d < D_; ++d) acc = fmaf(h[d], W2[(size_t)d * U_ + u], acc);
    ph[b * U_ + u] = acc + W2b[u] + W1b[u];
}

// K2: fused bf16 32x32x16-MFMA GEMM + tanh + V-dot -> lpart[uh][b][t]
// BARRIER-FREE K-loop: A (64 t x 512 k bf16, 64 KB) staged to LDS once
// (single barrier); B frags loaded straight from L2-resident W1T into VGPRs,
// pipelined one k32-step ahead (fine-grained vmcnt, no drain).
// 512 thr / 8 waves; each wave: all 64 t-rows x its own 64-u strip (acc 64 regs).
// u-split x2 via gx&1. A LDS: 16 panels of [64 rows][64 B], chunk q at
// q^((row>>2)&3) — the R4-measured 0-conflict scheme.
__global__ __launch_bounds__(512, 4) void logits_mfma_kernel(
    const float* __restrict__ feat,          // [B,T,D] fp32
    const unsigned short* __restrict__ W1T,  // [U,D] bf16
    const float* __restrict__ ph,            // [B,U] biases folded
    const float* __restrict__ Vw,            // [U]
    float* __restrict__ lpart) {             // [2][B][T]
    __shared__ __align__(16) char As[65536];  // 16 panels x 64 rows x 64 B

    const int tid  = threadIdx.x;
    const int gx   = blockIdx.x;        // uh fastest: A-sharing pair co-dispatch
    const int uh   = gx & 1;
    const int tt   = gx >> 1;
    const int b    = blockIdx.y;
    const int t0   = tt * 64;
    const int lane = tid & 63;
    const int widx = tid >> 6;
    const int l31 = lane & 31, g = lane >> 5;
    const int u0  = uh * 512 + widx * 64;   // wave's u-strip

    // ---- stage A once: feat[b, t0..t0+64, :] fp32 -> bf16 swizzled panels ----
    {
        const int r  = tid >> 3;       // 0..63
        const int s0 = tid & 7;
        const float* src = feat + ((size_t)(b * T_ + t0 + r)) * D_;
        const int xr = (r >> 2) & 3;
#pragma unroll
        for (int i = 0; i < 8; ++i) {
            const int s = s0 + 8 * i;            // 0..63 (16B slot in row)
            const float4 v0 = *(const float4*)(src + s * 8);
            const float4 v1 = *(const float4*)(src + s * 8 + 4);
            uint4 w;
            w.x = f2bf_pk(v0.x, v0.y);
            w.y = f2bf_pk(v0.z, v0.w);
            w.z = f2bf_pk(v1.x, v1.y);
            w.w = f2bf_pk(v1.z, v1.w);
            const int panel = s >> 2, q = s & 3;
            *(uint4*)&As[panel * 4096 + r * 64 + (q ^ xr) * 16] = w;
        }
    }
    __syncthreads();   // the ONLY barrier before the epilogue

    // ---- B global frag pointers: lane -> (u-row, k-half) ----
    // frag element k = kt*32 + (2*ks+g)*8 ; byte offset kt*64 + ks*32 + g*16
    const unsigned short* bp[2];
    bp[0] = W1T + (size_t)(u0 + l31) * D_ + g * 8;        // nt=0
    bp[1] = W1T + (size_t)(u0 + 32 + l31) * D_ + g * 8;   // nt=1

    auto loadB = [&](bf16x8* dst, int kt) {
#pragma unroll
        for (int nt = 0; nt < 2; ++nt)
#pragma unroll
            for (int ks = 0; ks < 2; ++ks)
                dst[nt * 2 + ks] = *(const bf16x8*)(bp[nt] + kt * 32 + ks * 16);
    };

    f32x16 acc[2][2];
#pragma unroll
    for (int mt = 0; mt < 2; ++mt)
#pragma unroll
        for (int nt = 0; nt < 2; ++nt) acc[mt][nt] = (f32x16)(0.f);

    auto computeStep = [&](int kt, const bf16x8* bfr) {
        bf16x8 af[2][2];   // [ks][mt]
#pragma unroll
        for (int ks = 0; ks < 2; ++ks)
#pragma unroll
            for (int mt = 0; mt < 2; ++mt) {
                const int rr = mt * 32 + l31;
                const int q  = (2 * ks + g) ^ ((rr >> 2) & 3);
                af[ks][mt] = *(const bf16x8*)&As[kt * 4096 + rr * 64 + q * 16];
            }
#pragma unroll
        for (int ks = 0; ks < 2; ++ks)
#pragma unroll
            for (int mt = 0; mt < 2; ++mt)
#pragma unroll
                for (int nt = 0; nt < 2; ++nt)
                    acc[mt][nt] = __builtin_amdgcn_mfma_f32_32x32x16_bf16(
                        af[ks][mt], bfr[nt * 2 + ks], acc[mt][nt], 0, 0, 0);
    };

    bf16x8 b0[4], b1[4];
    loadB(b0, 0);
    for (int kt = 0; kt < 16; kt += 2) {
        if (kt + 1 < 16) loadB(b1, kt + 1);
        computeStep(kt, b0);
        if (kt + 2 < 16) loadB(b0, kt + 2);
        computeStep(kt + 1, b1);
    }

    // ---- fused epilogue: tanh + V-dot, reduce over u ----
    float lp[2][16];
#pragma unroll
    for (int mt = 0; mt < 2; ++mt)
#pragma unroll
        for (int r = 0; r < 16; ++r) lp[mt][r] = 0.f;

#pragma unroll
    for (int nt = 0; nt < 2; ++nt) {
        const int u = u0 + nt * 32 + l31;
        const float phv = ph[b * U_ + u];
        const float vw  = Vw[u];
#pragma unroll
        for (int mt = 0; mt < 2; ++mt)
#pragma unroll
            for (int r = 0; r < 16; ++r)
                lp[mt][r] = fmaf(vw, fast_tanh(acc[mt][nt][r] + phv), lp[mt][r]);
    }
    // sum over 32 lane-columns (stays within each 32-lane half; g kept = row bit)
#pragma unroll
    for (int mt = 0; mt < 2; ++mt)
#pragma unroll
        for (int r = 0; r < 16; ++r) {
            float v = lp[mt][r];
            v += __shfl_xor(v, 1);
            v += __shfl_xor(v, 2);
            v += __shfl_xor(v, 4);
            v += __shfl_xor(v, 8);
            v += __shfl_xor(v, 16);
            lp[mt][r] = v;
        }
    __syncthreads();            // A no longer needed; reuse as scratch
    float* scr = (float*)&As[0];   // [64 rows][8 waves]
    if (l31 == 0) {
#pragma unroll
        for (int mt = 0; mt < 2; ++mt)
#pragma unroll
            for (int r = 0; r < 16; ++r) {
                const int row = mt * 32 + (r & 3) + 8 * (r >> 2) + 4 * g;
                scr[row * 8 + widx] = lp[mt][r];
            }
    }
    __syncthreads();
    if (tid < 64) {
        float s = 0.f;
#pragma unroll
        for (int x = 0; x < 8; ++x) s += scr[tid * 8 + x];
        lpart[((size_t)uh * B_ + b) * T_ + t0 + tid] = s;
    }
}

// K3: softmax over T from 2 u-half partials (Vb cancels)
__global__ __launch_bounds__(256) void softmax2_kernel(
    const float* __restrict__ lp, float* __restrict__ attn) {
    const int b = blockIdx.x;
    const int tid = threadIdx.x;
    __shared__ float redm[4];
    __shared__ float reds[4];
    float v[4];
    float mx = -3.4e38f;
#pragma unroll
    for (int j = 0; j < 4; ++j) {
        const int x = b * T_ + tid + 256 * j;
        v[j] = lp[x] + lp[B_ * T_ + x];
        mx = fmaxf(mx, v[j]);
    }
#pragma unroll
    for (int off = 32; off > 0; off >>= 1) mx = fmaxf(mx, __shfl_xor(mx, off));
    if ((tid & 63) == 0) redm[tid >> 6] = mx;
    __syncthreads();
    mx = fmaxf(fmaxf(redm[0], redm[1]), fmaxf(redm[2], redm[3]));
    float s = 0.f;
#pragma unroll
    for (int j = 0; j < 4; ++j) {
        v[j] = __expf(v[j] - mx);
        s += v[j];
    }
#pragma unroll
    for (int off = 32; off > 0; off >>= 1) s += __shfl_xor(s, off);
    if ((tid & 63) == 0) reds[tid >> 6] = s;
    __syncthreads();
    s = reds[0] + reds[1] + reds[2] + reds[3];
    const float inv = 1.0f / s;
#pragma unroll
    for (int j = 0; j < 4; ++j) attn[b * T_ + tid + 256 * j] = v[j] * inv;
}

// K4: context partials, float4, 16 t-segments. grid (8, B), block 256
__global__ __launch_bounds__(256) void context_partial_kernel(
    const float* __restrict__ feat, const float* __restrict__ attn,
    float* __restrict__ part) {
    const int b   = blockIdx.y;
    const int seg = blockIdx.x;
    const int d4  = (threadIdx.x & 127) * 4;
    const int h   = threadIdx.x >> 7;
    const int t0  = seg * 128 + h * 64;
    const float* fb = feat + ((size_t)b * T_ + t0) * D_ + d4;
    const float* wb = attn + b * T_ + t0;
    float4 acc = {0.f, 0.f, 0.f, 0.f};
#pragma unroll 4
    for (int t = 0; t < 64; ++t) {
        const float w  = wb[t];
        const float4 f = *(const float4*)&fb[(size_t)t * D_];
        acc.x = fmaf(w, f.x, acc.x);
        acc.y = fmaf(w, f.y, acc.y);
        acc.z = fmaf(w, f.z, acc.z);
        acc.w = fmaf(w, f.w, acc.w);
    }
    *(float4*)&part[((size_t)(b * 16 + seg * 2 + h)) * D_ + d4] = acc;
}

// K5: reduce 16 partials -> context. grid (B*D/256)
__global__ __launch_bounds__(256) void context_reduce_kernel(
    const float* __restrict__ part, float* __restrict__ ctx) {
    const int i = blockIdx.x * 256 + threadIdx.x;
    const int b = i >> 9;
    const int d = i & (D_ - 1);
    float s = 0.f;
#pragma unroll
    for (int g = 0; g < 16; ++g) s += part[((size_t)(b * 16 + g)) * D_ + d];
    ctx[i] = s;
}

extern "C" void kernel_launch(void* const* d_in, const int* in_sizes, int n_in,
                              void* d_out, int out_size, void* d_ws, size_t ws_size,
                              hipStream_t stream) {
    const float* feat   = (const float*)d_in[0];
    const float* hidden = (const float*)d_in[1];
    const float* W1w    = (const float*)d_in[2];
    const float* W1b    = (const float*)d_in[3];
    const float* W2w    = (const float*)d_in[4];
    const float* W2b    = (const float*)d_in[5];
    const float* Vw     = (const float*)d_in[6];
    // V_b cancels in softmax and doesn't affect context.

    float* out_ctx  = (float*)d_out;             // [B,D]
    float* out_attn = out_ctx + B_ * D_;         // [B,T]

    unsigned short* W1T = (unsigned short*)d_ws;             // U*D bf16 = 1 MB
    float* ph     = (float*)(W1T + (size_t)U_ * D_);         // B*U
    float* lpart  = ph + B_ * U_;                            // 2*B*T
    float* part   = lpart + 2 * B_ * T_;                     // B*16*D

    w1t_kernel<<<256, 256, 0, stream>>>(W1w, W1T);
    ph_kernel<<<dim3(U_ / 256, B_), 256, 0, stream>>>(hidden, W2w, W2b, W1b, ph);
    logits_mfma_kernel<<<dim3(32, B_), 512, 0, stream>>>(feat, W1T, ph, Vw, lpart);
    softmax2_kernel<<<B_, 256, 0, stream>>>(lpart, out_attn);
    context_partial_kernel<<<dim3(8, B_), 256, 0, stream>>>(feat, out_attn, part);
    context_reduce_kernel<<<B_ * D_ / 256, 256, 0, stream>>>(part, out_ctx);
}

// Round 7
// 338.479 us; speedup vs baseline: 1.1893x; 1.1893x over previous
//
#include <hip/hip_runtime.h>
#include <math.h>

#define B_ 64
#define T_ 1024
#define D_ 512
#define U_ 1024

typedef __bf16 bf16x8 __attribute__((ext_vector_type(8)));
typedef float f32x16 __attribute__((ext_vector_type(16)));
typedef unsigned int u32;

__device__ __forceinline__ float fast_tanh(float x) {
    float ax = fabsf(x);
    float e = __expf(2.0f * ax);
    float r = 1.0f - __fdividef(2.0f, e + 1.0f);
    return copysignf(r, x);
}

__device__ __forceinline__ u32 f2bf_pk(float lo, float hi) {
    u32 a = __float_as_uint(lo) + 0x8000u;
    u32 b = __float_as_uint(hi) + 0x8000u;
    return (a >> 16) | (b & 0xffff0000u);
}

// K_prep: blocks [0,256): W1 [D][U] fp32 -> W1F in MFMA-fragment order:
//   frag=(ut*16+kt)*2+ks holds B-frag for u-tile ut (32 u), k=kt*32+ks*16;
//   slot (frag,lane) = 8 bf16: u=ut*32+(lane&31), k0=kt*32+ks*16+(lane>>5)*8.
// blocks [256,512): ph[b][u] = hidden·W2 + W2_b + W1_b.
__global__ __launch_bounds__(256) void prep_kernel(
    const float* __restrict__ W1, const float* __restrict__ hidden,
    const float* __restrict__ W2, const float* __restrict__ W2b,
    const float* __restrict__ W1b,
    unsigned short* __restrict__ W1F, float* __restrict__ ph) {
    if (blockIdx.x < 256) {
        const int gid  = blockIdx.x * 256 + threadIdx.x;  // 0..65535
        const int lane = gid & 63;
        const int frag = gid >> 6;                        // 0..1023
        const int ks = frag & 1;
        const int kt = (frag >> 1) & 15;
        const int ut = frag >> 5;
        const int u  = ut * 32 + (lane & 31);
        const int k0 = kt * 32 + ks * 16 + (lane >> 5) * 8;
        float f[8];
#pragma unroll
        for (int j = 0; j < 8; ++j) f[j] = W1[(size_t)(k0 + j) * U_ + u];
        uint4 w;
        w.x = f2bf_pk(f[0], f[1]);
        w.y = f2bf_pk(f[2], f[3]);
        w.z = f2bf_pk(f[4], f[5]);
        w.w = f2bf_pk(f[6], f[7]);
        *(uint4*)&W1F[(size_t)gid * 8] = w;
    } else {
        const int bx = blockIdx.x - 256;
        const int u  = (bx & 3) * 256 + threadIdx.x;
        const int b  = bx >> 2;
        const float* h = hidden + b * D_;
        float acc = 0.f;
#pragma unroll 8
        for (int d = 0; d < D_; ++d) acc = fmaf(h[d], W2[(size_t)d * U_ + u], acc);
        ph[b * U_ + u] = acc + W2b[u] + W1b[u];
    }
}

// K2: fused bf16 32x32x16-MFMA GEMM + tanh + V-dot -> lpart[uh][b][t]
// Barrier-free K-loop (R6 structure). A (64 t x 512 k bf16, 64 KB) staged to
// LDS once; B frags loaded from W1F (fragment-order, fully coalesced
// global_load_dwordx4: base + frag*1024 + lane*16), double-buffered in regs.
__global__ __launch_bounds__(512, 4) void logits_mfma_kernel(
    const float* __restrict__ feat,          // [B,T,D] fp32
    const unsigned short* __restrict__ W1F,  // fragment-order bf16
    const float* __restrict__ ph,            // [B,U] biases folded
    const float* __restrict__ Vw,            // [U]
    float* __restrict__ lpart) {             // [2][B][T]
    __shared__ __align__(16) char As[65536];  // 16 panels x 64 rows x 64 B

    const int tid  = threadIdx.x;
    const int gx   = blockIdx.x;        // uh fastest: A-sharing pair co-dispatch
    const int uh   = gx & 1;
    const int tt   = gx >> 1;
    const int b    = blockIdx.y;
    const int t0   = tt * 64;
    const int lane = tid & 63;
    const int widx = tid >> 6;
    const int l31 = lane & 31, g = lane >> 5;
    const int u0  = uh * 512 + widx * 64;   // wave's u-strip

    // ---- stage A once: feat[b, t0..t0+64, :] fp32 -> bf16 swizzled panels ----
    {
        const int r  = tid >> 3;       // 0..63
        const int s0 = tid & 7;
        const float* src = feat + ((size_t)(b * T_ + t0 + r)) * D_;
        const int xr = (r >> 2) & 3;
#pragma unroll
        for (int i = 0; i < 8; ++i) {
            const int s = s0 + 8 * i;            // 16B slot in row
            const float4 v0 = *(const float4*)(src + s * 8);
            const float4 v1 = *(const float4*)(src + s * 8 + 4);
            uint4 w;
            w.x = f2bf_pk(v0.x, v0.y);
            w.y = f2bf_pk(v0.z, v0.w);
            w.z = f2bf_pk(v1.x, v1.y);
            w.w = f2bf_pk(v1.z, v1.w);
            const int panel = s >> 2, q = s & 3;
            *(uint4*)&As[panel * 4096 + r * 64 + (q ^ xr) * 16] = w;
        }
    }
    __syncthreads();   // the ONLY barrier before the epilogue

    // ---- B frag base: wave's u-tile ut = u0/32; nt adds one tile (32768 B) ----
    const char* bfbase = (const char*)W1F + (size_t)(u0 >> 5) * 32768 + lane * 16;
    auto loadB = [&](bf16x8* dst, int kt) {
#pragma unroll
        for (int nt = 0; nt < 2; ++nt)
#pragma unroll
            for (int ks = 0; ks < 2; ++ks)
                dst[nt * 2 + ks] =
                    *(const bf16x8*)(bfbase + nt * 32768 + (kt * 2 + ks) * 1024);
    };

    f32x16 acc[2][2];
#pragma unroll
    for (int mt = 0; mt < 2; ++mt)
#pragma unroll
        for (int nt = 0; nt < 2; ++nt) acc[mt][nt] = (f32x16)(0.f);

    auto computeStep = [&](int kt, const bf16x8* bfr) {
        bf16x8 af[2][2];   // [ks][mt]
#pragma unroll
        for (int ks = 0; ks < 2; ++ks)
#pragma unroll
            for (int mt = 0; mt < 2; ++mt) {
                const int rr = mt * 32 + l31;
                const int q  = (2 * ks + g) ^ ((rr >> 2) & 3);
                af[ks][mt] = *(const bf16x8*)&As[kt * 4096 + rr * 64 + q * 16];
            }
#pragma unroll
        for (int ks = 0; ks < 2; ++ks)
#pragma unroll
            for (int mt = 0; mt < 2; ++mt)
#pragma unroll
                for (int nt = 0; nt < 2; ++nt)
                    acc[mt][nt] = __builtin_amdgcn_mfma_f32_32x32x16_bf16(
                        af[ks][mt], bfr[nt * 2 + ks], acc[mt][nt], 0, 0, 0);
    };

    bf16x8 b0[4], b1[4];
    loadB(b0, 0);
    for (int kt = 0; kt < 16; kt += 2) {
        if (kt + 1 < 16) loadB(b1, kt + 1);
        computeStep(kt, b0);
        if (kt + 2 < 16) loadB(b0, kt + 2);
        computeStep(kt + 1, b1);
    }

    // ---- fused epilogue: tanh + V-dot, reduce over u ----
    float lp[2][16];
#pragma unroll
    for (int mt = 0; mt < 2; ++mt)
#pragma unroll
        for (int r = 0; r < 16; ++r) lp[mt][r] = 0.f;

#pragma unroll
    for (int nt = 0; nt < 2; ++nt) {
        const int u = u0 + nt * 32 + l31;
        const float phv = ph[b * U_ + u];
        const float vw  = Vw[u];
#pragma unroll
        for (int mt = 0; mt < 2; ++mt)
#pragma unroll
            for (int r = 0; r < 16; ++r)
                lp[mt][r] = fmaf(vw, fast_tanh(acc[mt][nt][r] + phv), lp[mt][r]);
    }
#pragma unroll
    for (int mt = 0; mt < 2; ++mt)
#pragma unroll
        for (int r = 0; r < 16; ++r) {
            float v = lp[mt][r];
            v += __shfl_xor(v, 1);
            v += __shfl_xor(v, 2);
            v += __shfl_xor(v, 4);
            v += __shfl_xor(v, 8);
            v += __shfl_xor(v, 16);
            lp[mt][r] = v;
        }
    __syncthreads();            // A no longer needed; reuse as scratch
    float* scr = (float*)&As[0];   // [64 rows][8 waves]
    if (l31 == 0) {
#pragma unroll
        for (int mt = 0; mt < 2; ++mt)
#pragma unroll
            for (int r = 0; r < 16; ++r) {
                const int row = mt * 32 + (r & 3) + 8 * (r >> 2) + 4 * g;
                scr[row * 8 + widx] = lp[mt][r];
            }
    }
    __syncthreads();
    if (tid < 64) {
        float s = 0.f;
#pragma unroll
        for (int x = 0; x < 8; ++x) s += scr[tid * 8 + x];
        lpart[((size_t)uh * B_ + b) * T_ + t0 + tid] = s;
    }
}

// K3: fused softmax + attn-write + context partial. grid (8 seg, B), block 256.
// Each block recomputes softmax stats from lpart (8 KB, L2-hot), writes its
// own attn t-slice, then accumulates its context partial from LDS weights.
__global__ __launch_bounds__(256) void ctx_kernel(
    const float* __restrict__ feat, const float* __restrict__ lpart,
    float* __restrict__ attn, float* __restrict__ part) {
    const int b   = blockIdx.y;
    const int seg = blockIdx.x;
    const int tid = threadIdx.x;
    __shared__ float wls[1024];
    __shared__ float redm[4];
    __shared__ float reds[4];

    float v[4];
    float mx = -3.4e38f;
#pragma unroll
    for (int j = 0; j < 4; ++j) {
        const int x = b * T_ + tid + 256 * j;
        v[j] = lpart[x] + lpart[B_ * T_ + x];
        mx = fmaxf(mx, v[j]);
    }
#pragma unroll
    for (int off = 32; off > 0; off >>= 1) mx = fmaxf(mx, __shfl_xor(mx, off));
    if ((tid & 63) == 0) redm[tid >> 6] = mx;
    __syncthreads();
    mx = fmaxf(fmaxf(redm[0], redm[1]), fmaxf(redm[2], redm[3]));
    float s = 0.f;
#pragma unroll
    for (int j = 0; j < 4; ++j) {
        v[j] = __expf(v[j] - mx);
        s += v[j];
    }
#pragma unroll
    for (int off = 32; off > 0; off >>= 1) s += __shfl_xor(s, off);
    if ((tid & 63) == 0) reds[tid >> 6] = s;
    __syncthreads();
    s = reds[0] + reds[1] + reds[2] + reds[3];
    const float inv = 1.0f / s;
#pragma unroll
    for (int j = 0; j < 4; ++j) wls[tid + 256 * j] = v[j] * inv;
    __syncthreads();

    // attn write: own slice only
    if (tid < 128) attn[b * T_ + seg * 128 + tid] = wls[seg * 128 + tid];

    // context partial over this segment's 128 t (2 halves of 64)
    const int d4 = (tid & 127) * 4;
    const int h  = tid >> 7;
    const int t0 = seg * 128 + h * 64;
    const float* fb = feat + ((size_t)b * T_ + t0) * D_ + d4;
    const float* wb = &wls[t0];
    float4 acc = {0.f, 0.f, 0.f, 0.f};
#pragma unroll 4
    for (int t = 0; t < 64; ++t) {
        const float w  = wb[t];
        const float4 f = *(const float4*)&fb[(size_t)t * D_];
        acc.x = fmaf(w, f.x, acc.x);
        acc.y = fmaf(w, f.y, acc.y);
        acc.z = fmaf(w, f.z, acc.z);
        acc.w = fmaf(w, f.w, acc.w);
    }
    *(float4*)&part[((size_t)(b * 16 + seg * 2 + h)) * D_ + d4] = acc;
}

// K4: reduce 16 partials -> context. grid (B*D/256)
__global__ __launch_bounds__(256) void context_reduce_kernel(
    const float* __restrict__ part, float* __restrict__ ctx) {
    const int i = blockIdx.x * 256 + threadIdx.x;
    const int b = i >> 9;
    const int d = i & (D_ - 1);
    float s = 0.f;
#pragma unroll
    for (int g = 0; g < 16; ++g) s += part[((size_t)(b * 16 + g)) * D_ + d];
    ctx[i] = s;
}

extern "C" void kernel_launch(void* const* d_in, const int* in_sizes, int n_in,
                              void* d_out, int out_size, void* d_ws, size_t ws_size,
                              hipStream_t stream) {
    const float* feat   = (const float*)d_in[0];
    const float* hidden = (const float*)d_in[1];
    const float* W1w    = (const float*)d_in[2];
    const float* W1b    = (const float*)d_in[3];
    const float* W2w    = (const float*)d_in[4];
    const float* W2b    = (const float*)d_in[5];
    const float* Vw     = (const float*)d_in[6];
    // V_b cancels in softmax and doesn't affect context.

    float* out_ctx  = (float*)d_out;             // [B,D]
    float* out_attn = out_ctx + B_ * D_;         // [B,T]

    unsigned short* W1F = (unsigned short*)d_ws;             // U*D bf16 = 1 MB
    float* ph     = (float*)(W1F + (size_t)U_ * D_);         // B*U
    float* lpart  = ph + B_ * U_;                            // 2*B*T
    float* part   = lpart + 2 * B_ * T_;                     // B*16*D

    prep_kernel<<<512, 256, 0, stream>>>(W1w, hidden, W2w, W2b, W1b, W1F, ph);
    logits_mfma_kernel<<<dim3(32, B_), 512, 0, stream>>>(feat, W1F, ph, Vw, lpart);
    ctx_kernel<<<dim3(8, B_), 256, 0, stream>>>(feat, lpart, out_attn, part);
    context_reduce_kernel<<<B_ * D_ / 256, 256, 0, stream>>>(part, out_ctx);
}